// Round 2
// baseline (444.131 us; speedup 1.0000x reference)
//
#include <hip/hip_runtime.h>

// Problem dims
#define S_ 32
#define T_ 64
#define B_ 64
#define V_ 32000
#define E_ 128
#define H_ 128
#define G_ 128
#define C_ 5

typedef short s8v __attribute__((ext_vector_type(8)));   // 8 bf16 payload
typedef __bf16 b8v __attribute__((ext_vector_type(8)));
typedef float f32x4 __attribute__((ext_vector_type(4)));

// --- MFMA wrapper: tolerate either builtin operand signature (short8 or bf16x8)
template <typename V>
__device__ inline auto mfma_sel(V a, V b, f32x4 c, int)
    -> decltype(__builtin_amdgcn_mfma_f32_16x16x32_bf16(a, b, c, 0, 0, 0)) {
  return __builtin_amdgcn_mfma_f32_16x16x32_bf16(a, b, c, 0, 0, 0);
}
template <typename V>
__device__ inline f32x4 mfma_sel(V a, V b, f32x4 c, long) {
  return __builtin_amdgcn_mfma_f32_16x16x32_bf16(
      __builtin_bit_cast(b8v, a), __builtin_bit_cast(b8v, b), c, 0, 0, 0);
}
__device__ inline f32x4 mfma16(s8v a, s8v b, f32x4 c) { return mfma_sel(a, b, c, 0); }

__device__ inline float b2f(unsigned short u) {
  union { unsigned int i; float f; } v; v.i = ((unsigned int)u) << 16; return v.f;
}
__device__ inline unsigned short f2b(float f) {
  union { float f; unsigned int i; } v; v.f = f;
  unsigned int r = (v.i + 0x7fffu + ((v.i >> 16) & 1u)) >> 16;
  return (unsigned short)r;
}
// 8 consecutive fp32 -> bf16x8 fragment (RNE)
__device__ inline s8v cvt8(const float* p) {
  const float4 a = *(const float4*)p;
  const float4 b = *(const float4*)(p + 4);
  s8v r;
  r[0] = (short)f2b(a.x); r[1] = (short)f2b(a.y);
  r[2] = (short)f2b(a.z); r[3] = (short)f2b(a.w);
  r[4] = (short)f2b(b.x); r[5] = (short)f2b(b.y);
  r[6] = (short)f2b(b.z); r[7] = (short)f2b(b.w);
  return r;
}
__device__ inline float sigm(float x) {
  x = fminf(fmaxf(x, -30.f), 30.f);
  return 1.f / (1.f + __expf(-x));
}
__device__ inline float tanh_f(float x) {
  x = fminf(fmaxf(x, -15.f), 15.f);
  float e = __expf(2.f * x);
  return (e - 1.f) / (e + 1.f);
}

// ============================================================================
// K1: gtab[v][c] = sum_e emb[v][e] * Wih_intra[c][e] + bih[c]   (c = dir*384+g)
// fp32 in -> bf16 internal table. GEMM M=32000 N=768 K=128, MFMA.
// Block 3000 transposes W_W_intra (fp32) -> wta bf16 [n][k] for k_attn1.
// ============================================================================
__global__ __launch_bounds__(256) void k_gtab(
    const float* __restrict__ emb,
    const float* __restrict__ wih,   // [768][128] fp32
    const float* __restrict__ bih,   // [768] fp32
    const float* __restrict__ wwi,   // [256][256] fp32 (h-major)
    unsigned short* __restrict__ gtab,   // [V][768] bf16
    unsigned short* __restrict__ wta)    // [256][256] bf16 (n-major)
{
  const int bid = blockIdx.x, tid = threadIdx.x;
  if (bid == 3000) {  // transpose + bf16-ify W_W_intra
    for (int k = 0; k < 256; ++k) wta[tid * 256 + k] = f2b(wwi[k * 256 + tid]);
    return;
  }
  const int mchunk = bid / 6, nchunk = bid % 6;
  const int vbase = mchunk * 64, nbase = nchunk * 128;
  __shared__ __align__(16) unsigned short alds[64 * 136];
  for (int i = 0; i < 8; ++i) {
    int cid = i * 256 + tid;           // 2048 chunks of 4 floats
    int row = cid >> 5, kc = cid & 31;
    float4 v = *(const float4*)&emb[(size_t)(vbase + row) * 128 + kc * 4];
    ushort4 u; u.x = f2b(v.x); u.y = f2b(v.y); u.z = f2b(v.z); u.w = f2b(v.w);
    *(ushort4*)&alds[row * 136 + kc * 4] = u;
  }
  __syncthreads();
  const int w = tid >> 6, l = tid & 63, q = l >> 4, ln = l & 15;
  s8v bf[2][4];
  float bias[2];
  for (int nt = 0; nt < 2; ++nt) {
    int c = nbase + (w * 2 + nt) * 16 + ln;
    bias[nt] = bih[c];
    for (int kf = 0; kf < 4; ++kf)
      bf[nt][kf] = cvt8(&wih[(size_t)c * 128 + kf * 32 + q * 8]);
  }
  for (int mt = 0; mt < 4; ++mt) {
    s8v af[4];
    for (int kf = 0; kf < 4; ++kf)
      af[kf] = *(const s8v*)&alds[(mt * 16 + ln) * 136 + kf * 32 + q * 8];
    for (int nt = 0; nt < 2; ++nt) {
      f32x4 acc = {0.f, 0.f, 0.f, 0.f};
      for (int kf = 0; kf < 4; ++kf) acc = mfma16(af[kf], bf[nt][kf], acc);
      const int col = nbase + (w * 2 + nt) * 16 + ln;
      for (int r = 0; r < 4; ++r) {
        const int row = vbase + mt * 16 + q * 4 + r;
        gtab[(size_t)row * 768 + col] = f2b(acc[r] + bias[nt]);
      }
    }
  }
}

// ============================================================================
// K2: intra biGRU recurrence. Grid 256 = (s, dir, b-quad of 16). 512 thr.
// Per step: gh = Whh . h^T via MFMA (M=384 gates, N=16 batch, K=128).
// fp32 h kept in registers; bf16 copy in LDS feeds the MFMA B-operand.
// ============================================================================
__global__ __launch_bounds__(512) void k_intra(
    const int* __restrict__ tokens,
    const unsigned short* __restrict__ gtab,  // bf16 internal
    const float* __restrict__ whh,            // [2][384][128] fp32
    const float* __restrict__ bhh,            // [2][384] fp32
    unsigned short* __restrict__ iout)        // [S*T*B][256] bf16 internal
{
  const int bid = blockIdx.x;
  const int s = bid >> 3, dir = (bid >> 2) & 1, bq = bid & 3;
  const int bbase = bq * 16;
  const int tid = threadIdx.x;
  const int w = tid >> 6, l = tid & 63, q = l >> 4, ln = l & 15;
  const int gbase = w * 16, g0 = gbase + q * 4;

  __shared__ __align__(16) unsigned short hlds[16 * 136];
  __shared__ int tokl[T_ * 16];

  for (int i = tid; i < 16 * 136; i += 512) hlds[i] = 0;
  for (int i = tid; i < T_ * 16; i += 512) {
    int t = i >> 4, bl = i & 15;
    tokl[i] = tokens[(s * T_ + t) * B_ + bbase + bl];
  }

  s8v af[3][4];
  float hb[3][4];
  const float* whd = whh + (size_t)dir * (384 * 128);
  const float* bhd = bhh + dir * 384;
  for (int g3 = 0; g3 < 3; ++g3) {
    const int R = g3 * 128 + gbase;
    for (int kf = 0; kf < 4; ++kf)
      af[g3][kf] = cvt8(&whd[(size_t)(R + ln) * 128 + kf * 32 + q * 8]);
    for (int r = 0; r < 4; ++r)
      hb[g3][r] = bhd[R + q * 4 + r];
  }
  float h[4] = {0.f, 0.f, 0.f, 0.f};
  const int b = bbase + ln;
  __syncthreads();

  for (int step = 0; step < T_; ++step) {
    const int t = dir ? (T_ - 1 - step) : step;
    // issue gate-input gather early; consumed after the MFMA
    const int tok = tokl[t * 16 + ln];
    const unsigned short* gr = gtab + (size_t)tok * 768 + dir * 384 + g0;
    const ushort4 xr = *(const ushort4*)&gr[0];
    const ushort4 xz = *(const ushort4*)&gr[128];
    const ushort4 xn = *(const ushort4*)&gr[256];

    s8v bfr[4];
    for (int kf = 0; kf < 4; ++kf)
      bfr[kf] = *(const s8v*)&hlds[ln * 136 + kf * 32 + q * 8];
    f32x4 c0 = {0.f, 0.f, 0.f, 0.f}, c1 = c0, c2 = c0;
    for (int kf = 0; kf < 4; ++kf) {
      c0 = mfma16(af[0][kf], bfr[kf], c0);
      c1 = mfma16(af[1][kf], bfr[kf], c1);
      c2 = mfma16(af[2][kf], bfr[kf], c2);
    }
    __syncthreads();  // all reads of hlds done before anyone writes

    const unsigned short* xrp = (const unsigned short*)&xr;
    const unsigned short* xzp = (const unsigned short*)&xz;
    const unsigned short* xnp = (const unsigned short*)&xn;
    unsigned short hnb[4];
    for (int r = 0; r < 4; ++r) {
      float rr = sigm(b2f(xrp[r]) + c0[r] + hb[0][r]);
      float zz = sigm(b2f(xzp[r]) + c1[r] + hb[1][r]);
      float nn = tanh_f(b2f(xnp[r]) + rr * (c2[r] + hb[2][r]));
      float hv = (1.f - zz) * nn + zz * h[r];
      h[r] = hv;
      hnb[r] = f2b(hv);
    }
    ushort4 hv4; hv4.x = hnb[0]; hv4.y = hnb[1]; hv4.z = hnb[2]; hv4.w = hnb[3];
    *(ushort4*)&hlds[ln * 136 + g0] = hv4;
    *(ushort4*)&iout[((size_t)(s * T_ + t) * B_ + b) * 256 + dir * 128 + g0] = hv4;
    __syncthreads();  // writes visible before next step's reads
  }
}

// ============================================================================
// K3a: a1 logits = proj . tanh(iout @ W_W_intra + b). GEMM M=131072 N=256 K=256
// fused with tanh + proj-dot. Two launches (half of N each, 64KB LDS for Wt).
// ============================================================================
__global__ __launch_bounds__(256) void k_attn1(
    const unsigned short* __restrict__ iout,  // bf16 internal
    const unsigned short* __restrict__ wta,   // bf16 [256][256] n-major
    const float* __restrict__ bint,           // [256] fp32
    const float* __restrict__ proj,           // [256] fp32
    float* __restrict__ a1p, float* __restrict__ a1, int half)
{
  __shared__ __align__(16) unsigned short wlds[128 * 256];  // 64 KB, XOR-swizzled
  const int tid = threadIdx.x, bid = blockIdx.x;
  const int nbg = half * 128;
  for (int i = 0; i < 16; ++i) {
    int cid = i * 256 + tid;          // 4096 16B chunks
    int n = cid >> 5, kc = cid & 31;
    *(int4*)&wlds[n * 256 + ((kc ^ (n & 15)) << 3)] =
        *(const int4*)&wta[(size_t)(nbg + n) * 256 + kc * 8];
  }
  __syncthreads();
  const int w = tid >> 6, l = tid & 63, q = l >> 4, ln = l & 15;
  const int rbase = bid * 512;
  for (int mt8 = 0; mt8 < 8; ++mt8) {
    const int mt = w * 8 + mt8;
    const int rowa = rbase + mt * 16 + ln;
    s8v af[8];
    for (int kf = 0; kf < 8; ++kf)
      af[kf] = *(const s8v*)&iout[(size_t)rowa * 256 + kf * 32 + q * 8];
    float p0 = 0.f, p1 = 0.f, p2 = 0.f, p3 = 0.f;
    for (int nt = 0; nt < 8; ++nt) {
      const int nloc = nt * 16 + ln;
      f32x4 c = {0.f, 0.f, 0.f, 0.f};
      for (int kf = 0; kf < 8; ++kf) {
        s8v bf = *(const s8v*)&wlds[nloc * 256 + (((kf * 4 + q) ^ (nloc & 15)) << 3)];
        c = mfma16(af[kf], bf, c);
      }
      const int ncol = nbg + nloc;
      const float bb = bint[ncol], pp = proj[ncol];
      p0 += pp * tanh_f(c[0] + bb);
      p1 += pp * tanh_f(c[1] + bb);
      p2 += pp * tanh_f(c[2] + bb);
      p3 += pp * tanh_f(c[3] + bb);
    }
    for (int d = 1; d < 16; d <<= 1) {
      p0 += __shfl_xor(p0, d);
      p1 += __shfl_xor(p1, d);
      p2 += __shfl_xor(p2, d);
      p3 += __shfl_xor(p3, d);
    }
    if (ln == 0) {
      const int row = rbase + mt * 16 + q * 4;
      if (half == 0) {
        a1p[row] = p0; a1p[row + 1] = p1; a1p[row + 2] = p2; a1p[row + 3] = p3;
      } else {
        a1[row]     = a1p[row]     + p0;
        a1[row + 1] = a1p[row + 1] + p1;
        a1[row + 2] = a1p[row + 2] + p2;
        a1[row + 3] = a1p[row + 3] + p3;
      }
    }
  }
}

// ============================================================================
// K3b: softmax over T per (s,b) + weighted sum -> sent_vecs fp32 [S*B][256]
// ============================================================================
__global__ __launch_bounds__(256) void k_attn2(
    const float* __restrict__ a1,
    const unsigned short* __restrict__ iout,
    float* __restrict__ sv)
{
  const int bid = blockIdx.x;
  const int s = bid >> 6, b = bid & 63;
  const int tid = threadIdx.x;
  __shared__ float wgt[T_];
  if (tid < 64) {
    float lg = a1[(s * T_ + tid) * B_ + b];
    float m = lg;
    for (int d = 1; d < 64; d <<= 1) m = fmaxf(m, __shfl_xor(m, d));
    float e = __expf(lg - m);
    float sum = e;
    for (int d = 1; d < 64; d <<= 1) sum += __shfl_xor(sum, d);
    wgt[tid] = e / sum;
  }
  __syncthreads();
  float acc = 0.f;
  for (int t = 0; t < T_; ++t)
    acc += wgt[t] * b2f(iout[((size_t)(s * T_ + t) * B_ + b) * 256 + tid]);
  sv[(size_t)(s * B_ + b) * 256 + tid] = acc;
}

// ============================================================================
// K4: inter input gates xgi[dir][s*64+b][384] = sv @ Wih_inter^T + bih_inter
// ============================================================================
__global__ __launch_bounds__(256) void k_xgi(
    const float* __restrict__ sv,
    const float* __restrict__ wihI,  // [768][256] fp32
    const float* __restrict__ bihI,  // [768] fp32
    float* __restrict__ xgi)         // [2][2048][384]
{
  const int bid = blockIdx.x, tid = threadIdx.x;
  const int r0 = bid * 8;
  __shared__ float svl[8 * 256];
  for (int i = 0; i < 8; ++i) svl[i * 256 + tid] = sv[(size_t)(r0 + i) * 256 + tid];
  __syncthreads();
  for (int cc = 0; cc < 3; ++cc) {
    const int c = cc * 256 + tid;
    const float bias = bihI[c];
    float acc[8];
    for (int i = 0; i < 8; ++i) acc[i] = bias;
    const float* wr = wihI + (size_t)c * 256;
    for (int hh = 0; hh < 256; ++hh) {
      const float wv = wr[hh];
      for (int i = 0; i < 8; ++i) acc[i] += wv * svl[i * 256 + hh];
    }
    const int dir = c / 384, g = c % 384;
    for (int i = 0; i < 8; ++i)
      xgi[((size_t)dir * 2048 + r0 + i) * 384 + g] = acc[i];
  }
}

// ============================================================================
// K5: inter biGRU. Grid 8 = (dir, b-quad). Same structure as k_intra.
// ============================================================================
__global__ __launch_bounds__(512) void k_inter(
    const float* __restrict__ xgi,
    const float* __restrict__ whh,   // [2][384][128] fp32
    const float* __restrict__ bhh,   // [2][384] fp32
    float* __restrict__ io2)         // [S*B][256] fp32
{
  const int bid = blockIdx.x;
  const int dir = bid >> 2, bq = bid & 3, bbase = bq * 16;
  const int tid = threadIdx.x;
  const int w = tid >> 6, l = tid & 63, q = l >> 4, ln = l & 15;
  const int gbase = w * 16, g0 = gbase + q * 4;
  __shared__ __align__(16) unsigned short hlds[16 * 136];
  for (int i = tid; i < 16 * 136; i += 512) hlds[i] = 0;
  s8v af[3][4];
  float hb[3][4];
  const float* whd = whh + (size_t)dir * (384 * 128);
  const float* bhd = bhh + dir * 384;
  for (int g3 = 0; g3 < 3; ++g3) {
    const int R = g3 * 128 + gbase;
    for (int kf = 0; kf < 4; ++kf)
      af[g3][kf] = cvt8(&whd[(size_t)(R + ln) * 128 + kf * 32 + q * 8]);
    for (int r = 0; r < 4; ++r)
      hb[g3][r] = bhd[R + q * 4 + r];
  }
  float h[4] = {0.f, 0.f, 0.f, 0.f};
  const int b = bbase + ln;
  __syncthreads();
  for (int step = 0; step < S_; ++step) {
    const int sI = dir ? (S_ - 1 - step) : step;
    const float* xp = xgi + ((size_t)dir * 2048 + sI * 64 + b) * 384 + g0;
    const float4 vr = *(const float4*)&xp[0];
    const float4 vz = *(const float4*)&xp[128];
    const float4 vn = *(const float4*)&xp[256];
    s8v bfr[4];
    for (int kf = 0; kf < 4; ++kf)
      bfr[kf] = *(const s8v*)&hlds[ln * 136 + kf * 32 + q * 8];
    f32x4 c0 = {0.f, 0.f, 0.f, 0.f}, c1 = c0, c2 = c0;
    for (int kf = 0; kf < 4; ++kf) {
      c0 = mfma16(af[0][kf], bfr[kf], c0);
      c1 = mfma16(af[1][kf], bfr[kf], c1);
      c2 = mfma16(af[2][kf], bfr[kf], c2);
    }
    __syncthreads();
    const float irv[4] = {vr.x, vr.y, vr.z, vr.w};
    const float izv[4] = {vz.x, vz.y, vz.z, vz.w};
    const float inv[4] = {vn.x, vn.y, vn.z, vn.w};
    unsigned short hnb[4];
    for (int r = 0; r < 4; ++r) {
      float rr = sigm(irv[r] + c0[r] + hb[0][r]);
      float zz = sigm(izv[r] + c1[r] + hb[1][r]);
      float nn = tanh_f(inv[r] + rr * (c2[r] + hb[2][r]));
      float hv = (1.f - zz) * nn + zz * h[r];
      h[r] = hv;
      hnb[r] = f2b(hv);
    }
    ushort4 hv4; hv4.x = hnb[0]; hv4.y = hnb[1]; hv4.z = hnb[2]; hv4.w = hnb[3];
    *(ushort4*)&hlds[ln * 136 + g0] = hv4;
    float4 of4; of4.x = h[0]; of4.y = h[1]; of4.z = h[2]; of4.w = h[3];
    *(float4*)&io2[((size_t)(sI * 64 + b)) * 256 + dir * 128 + g0] = of4;
    __syncthreads();
  }
}

// ============================================================================
// K6: a2[s*64+b] = proj_inter . tanh(io2 @ W_W_inter + b_inter)  (no softmax)
// ============================================================================
__global__ __launch_bounds__(256) void k_attn_i(
    const float* __restrict__ io2,
    const float* __restrict__ wwI,   // [256][256] fp32 h-major
    const float* __restrict__ bI,
    const float* __restrict__ projI,
    float* __restrict__ a2)          // [2048]
{
  const int bid = blockIdx.x, tid = threadIdx.x;
  const int r0 = bid * 8;
  __shared__ float iol[8 * 256];
  __shared__ float red[4 * 8];
  for (int i = 0; i < 8; ++i) iol[i * 256 + tid] = io2[(size_t)(r0 + i) * 256 + tid];
  __syncthreads();
  float acc[8];
  for (int i = 0; i < 8; ++i) acc[i] = 0.f;
  for (int hh = 0; hh < 256; ++hh) {
    const float wv = wwI[hh * 256 + tid];
    for (int i = 0; i < 8; ++i) acc[i] += wv * iol[i * 256 + hh];
  }
  const float bb = bI[tid], pp = projI[tid];
  float p[8];
  for (int i = 0; i < 8; ++i) p[i] = pp * tanh_f(acc[i] + bb);
  for (int d = 1; d < 64; d <<= 1)
    for (int i = 0; i < 8; ++i) p[i] += __shfl_xor(p[i], d);
  const int w = tid >> 6, l = tid & 63;
  if (l == 0)
    for (int i = 0; i < 8; ++i) red[w * 8 + i] = p[i];
  __syncthreads();
  if (tid < 8) a2[r0 + tid] = red[tid] + red[8 + tid] + red[16 + tid] + red[24 + tid];
}

// ============================================================================
// K7: doc_vec = sum_s a2 * io2 ; out = doc @ W_final^T + b_final  (fp32 out)
// ============================================================================
__global__ __launch_bounds__(256) void k_final(
    const float* __restrict__ a2,
    const float* __restrict__ io2,
    const float* __restrict__ wf,    // [5][256] fp32
    const float* __restrict__ bfi,   // [5] fp32
    float* __restrict__ out)         // [64][5] fp32
{
  const int b = blockIdx.x, tid = threadIdx.x;
  __shared__ float av[S_];
  __shared__ float dv[256];
  __shared__ float red[4];
  if (tid < S_) av[tid] = a2[tid * 64 + b];
  __syncthreads();
  float acc = 0.f;
  for (int s = 0; s < S_; ++s) acc += av[s] * io2[((size_t)(s * 64 + b)) * 256 + tid];
  dv[tid] = acc;
  __syncthreads();
  for (int c = 0; c < C_; ++c) {
    float pv = wf[c * 256 + tid] * dv[tid];
    for (int d = 1; d < 64; d <<= 1) pv += __shfl_xor(pv, d);
    const int w = tid >> 6, l = tid & 63;
    if (l == 0) red[w] = pv;
    __syncthreads();
    if (tid == 0)
      out[b * C_ + c] = red[0] + red[1] + red[2] + red[3] + bfi[c];
    __syncthreads();
  }
}

// ============================================================================
extern "C" void kernel_launch(void* const* d_in, const int* in_sizes, int n_in,
                              void* d_out, int out_size, void* d_ws, size_t ws_size,
                              hipStream_t stream) {
  (void)in_sizes; (void)n_in; (void)out_size; (void)ws_size;
  const int*   tokens = (const int*)d_in[0];
  const float* emb    = (const float*)d_in[1];
  const float* wih_a  = (const float*)d_in[2];
  const float* whh_a  = (const float*)d_in[3];
  const float* bih_a  = (const float*)d_in[4];
  const float* bhh_a  = (const float*)d_in[5];
  const float* ww_a   = (const float*)d_in[6];
  const float* b_a    = (const float*)d_in[7];
  const float* proj_a = (const float*)d_in[8];
  const float* wih_i  = (const float*)d_in[9];
  const float* whh_i  = (const float*)d_in[10];
  const float* bih_i  = (const float*)d_in[11];
  const float* bhh_i  = (const float*)d_in[12];
  const float* ww_i   = (const float*)d_in[13];
  const float* b_i    = (const float*)d_in[14];
  const float* proj_i = (const float*)d_in[15];
  const float* w_fin  = (const float*)d_in[16];
  const float* b_fin  = (const float*)d_in[17];

  char* ws = (char*)d_ws;
  unsigned short* gtab = (unsigned short*)(ws + 0);          // 49,152,000 B
  unsigned short* wta  = (unsigned short*)(ws + 49152000);   //    131,072 B
  unsigned short* iout = (unsigned short*)(ws + 49283072);   // 67,108,864 B
  float* a1p = (float*)(ws + 116391936);                     //    524,288 B
  float* a1  = (float*)(ws + 116916224);                     //    524,288 B
  float* sv  = (float*)(ws + 117440512);                     //  2,097,152 B
  float* xgi = (float*)(ws + 119537664);                     //  6,291,456 B
  float* io2 = (float*)(ws + 125829120);                     //  2,097,152 B
  float* a2  = (float*)(ws + 127926272);                     //      8,192 B

  k_gtab<<<3001, 256, 0, stream>>>(emb, wih_a, bih_a, ww_a, gtab, wta);
  k_intra<<<256, 512, 0, stream>>>(tokens, gtab, whh_a, bhh_a, iout);
  k_attn1<<<256, 256, 0, stream>>>(iout, wta, b_a, proj_a, a1p, a1, 0);
  k_attn1<<<256, 256, 0, stream>>>(iout, wta, b_a, proj_a, a1p, a1, 1);
  k_attn2<<<2048, 256, 0, stream>>>(a1, iout, sv);
  k_xgi<<<256, 256, 0, stream>>>(sv, wih_i, bih_i, xgi);
  k_inter<<<8, 512, 0, stream>>>(xgi, whh_i, bhh_i, io2);
  k_attn_i<<<256, 256, 0, stream>>>(io2, ww_i, b_i, proj_i, a2);
  k_final<<<64, 256, 0, stream>>>(a2, io2, w_fin, b_fin, (float*)d_out);
}